// Round 15
// baseline (365.563 us; speedup 1.0000x reference)
//
#include <hip/hip_runtime.h>
#include <math.h>

#define KNN    10
#define NPTS   8192
#define HID    64
#define NF     76
#define CAP    64                 // pass-2 collection capacity per query
#define MARGIN 1.6e-2f            // covers 2*eps of split-bf16 dot (~2e-3) with 8x headroom
#define F32_INF __uint_as_float(0x7F800000u)

typedef __attribute__((ext_vector_type(8))) short bf16x8;
typedef __attribute__((ext_vector_type(4))) float f32x4;

__device__ __forceinline__ unsigned short bf16rn(float x) {
    const unsigned int u = __float_as_uint(x);
    return (unsigned short)((u + 0x7FFFu + ((u >> 16) & 1u)) >> 16);
}
__device__ __forceinline__ float bf16tof(unsigned short h) {
    return __uint_as_float(((unsigned int)h) << 16);
}

// ---------------------------------------------------------------------------
// Prep: pts4 (f32, unchanged chain), pw (f32 ||p||^2 array), and the 32B
// split-bf16 candidate record: k0..15 = [ph(3), ph(3), pl(3), pl(3), 0x4]
// pairing the A-side query layout [qh(3), ql(3), qh(3), ql(3)] so that
// sum_k A[k]B[k] = (qh+ql)·(ph+pl) per coordinate.
// ---------------------------------------------------------------------------
__global__ __launch_bounds__(256) void prep_kernel(const float* __restrict__ cloud,
                                                   float4* __restrict__ pts4,
                                                   uint4* __restrict__ bfrec,
                                                   float* __restrict__ pw) {
    const int i = blockIdx.x * 256 + threadIdx.x;      // 0..32767
    const float x = cloud[i * 3 + 0];
    const float y = cloud[i * 3 + 1];
    const float z = cloud[i * 3 + 2];
    const float w = fmaf(z, z, fmaf(y, y, x * x));
    pts4[i] = make_float4(x, y, z, w);
    pw[i] = w;
    const unsigned short xh = bf16rn(x), yh = bf16rn(y), zh = bf16rn(z);
    const unsigned short xl = bf16rn(x - bf16tof(xh));
    const unsigned short yl = bf16rn(y - bf16tof(yh));
    const unsigned short zl = bf16rn(z - bf16tof(zh));
    uint4 r0, r1;
    r0.x = (unsigned)xh | ((unsigned)yh << 16);   // k0,k1
    r0.y = (unsigned)zh | ((unsigned)xh << 16);   // k2,k3
    r0.z = (unsigned)yh | ((unsigned)zh << 16);   // k4,k5
    r0.w = (unsigned)xl | ((unsigned)yl << 16);   // k6,k7
    r1.x = (unsigned)zl | ((unsigned)xl << 16);   // k8,k9
    r1.y = (unsigned)yl | ((unsigned)zl << 16);   // k10,k11
    r1.z = 0u; r1.w = 0u;                         // k12..15
    bfrec[i * 2 + 0] = r0;
    bfrec[i * 2 + 1] = r1;
}

// ---------------------------------------------------------------------------
// KNN — MFMA distance scan (both passes), selection semantics identical to
// the validated R10-R14 chain:
//  - dot(q,p) via mfma_f32_16x16x32_bf16 with split-bf16 K=12 packing
//    (exact up to eps<=~1e-3); v~ = fmaf(-2, dot~, pw). IDENTICAL instr
//    sequence in pass 1 & 2 -> bit-identical v~ -> airtight superset logic.
//  - pass 1: per (query, 512-cand segment) min of v~ (16 segments/query);
//    tau = 11th-smallest of 16 + MARGIN (rank bound: >=10 non-self segment
//    minima <= m_(11); MARGIN >= 2*eps covers the approx error).
//  - pass 2: v~ <= tau filter; rare hits recompute EXACT f32 d2
//    (fmaf(-2,dot,qs+pw), R1-expression) -> keys bitwise-identical ->
//    phase-3 top-11 + self-filter gives the same stable top-10 == jax top_k.
//  - C/D layout (m89/m91-verified): col=lane&15 -> candidate, 
//    row=(lane>>4)*4+reg -> query.
// Block = 512 thr = 8 waves = 2 query-groups x 4 candidate-quarters
// (128 tiles of 16 cands each); grid 1024.
// ---------------------------------------------------------------------------
__global__ __launch_bounds__(512) void knn_kernel(const float4* __restrict__ pts4,
                                                  const uint4* __restrict__ bfrec,
                                                  const float* __restrict__ pw,
                                                  unsigned short* __restrict__ knn_idx) {
    __shared__ unsigned long long coll[CAP][33];   // [slot][block query+pad], 16.9 KB
    __shared__ float pk[2][16][17];                // [group][segment][query+pad]
    __shared__ float tau_s[32];
    __shared__ int   cnt[32];

    const int t    = threadIdx.x;
    const int w    = t >> 6;                  // wave 0..7
    const int lane = t & 63;
    const int g    = w >> 2;                  // query group 0..1
    const int h    = w & 3;                   // candidate quarter 0..3
    const int bx   = blockIdx.x;              // 0..1023
    const int b    = bx >> 8;                 // batch
    const int n_base = (bx & 255) * 32 + g * 16;  // batch-local first query of group
    const int lq_base = g * 16;               // block-local query base
    const int cb0 = h * (NPTS / 4);           // candidate base for this wave

    const float4* pb  = pts4 + b * NPTS;
    const uint4*  bfp = bfrec + (size_t)b * NPTS * 2;
    const float*  pwp = pw + b * NPTS;

    if (t < 32) cnt[t] = 0;                   // visible after barrier 1

    const int am = lane & 15;                 // MFMA col (candidate within tile)
    const int aq = lane >> 4;                 // MFMA quad

    // ---- A fragment: queries, layout A[m=lane&15][k=quad*8+j] ----
    bf16x8 afrag = (bf16x8)(short)0;
    {
        const float4 qv = pb[n_base + am];
        const unsigned short xh = bf16rn(qv.x), yh = bf16rn(qv.y), zh = bf16rn(qv.z);
        const unsigned short xl = bf16rn(qv.x - bf16tof(xh));
        const unsigned short yl = bf16rn(qv.y - bf16tof(yh));
        const unsigned short zl = bf16rn(qv.z - bf16tof(zh));
        if (aq == 0) {            // k0..7 of [qh(3),ql(3),qh(3),ql(3)]
            afrag = (bf16x8){(short)xh,(short)yh,(short)zh,(short)xl,
                             (short)yl,(short)zl,(short)xh,(short)yh};
        } else if (aq == 1) {     // k8..15
            afrag = (bf16x8){(short)zh,(short)xl,(short)yl,(short)zl,0,0,0,0};
        }
    }

    // this lane's 4 query rows (m = aq*4 + r), f32 for exact key rebuild
    const float4 qf0 = pb[n_base + aq * 4 + 0];
    const float4 qf1 = pb[n_base + aq * 4 + 1];
    const float4 qf2 = pb[n_base + aq * 4 + 2];
    const float4 qf3 = pb[n_base + aq * 4 + 3];

    const uint4 zrec = make_uint4(0u, 0u, 0u, 0u);

    // ---------------- pass 1: segment minima of v~ ----------------
#pragma unroll
    for (int seg = 0; seg < 4; ++seg) {
        float vm0 = F32_INF, vm1 = F32_INF, vm2 = F32_INF, vm3 = F32_INF;
        for (int ti = 0; ti < 32; ++ti) {
            const int c0 = cb0 + seg * 512 + ti * 16;
            const uint4 brec = (aq < 2) ? bfp[(size_t)(c0 + am) * 2 + aq] : zrec;
            const bf16x8 bfrag = __builtin_bit_cast(bf16x8, brec);
            const float pwv = pwp[c0 + am];
            f32x4 acc = {0.f, 0.f, 0.f, 0.f};
            acc = __builtin_amdgcn_mfma_f32_16x16x32_bf16(afrag, bfrag, acc, 0, 0, 0);
            vm0 = fminf(vm0, fmaf(-2.0f, acc[0], pwv));
            vm1 = fminf(vm1, fmaf(-2.0f, acc[1], pwv));
            vm2 = fminf(vm2, fmaf(-2.0f, acc[2], pwv));
            vm3 = fminf(vm3, fmaf(-2.0f, acc[3], pwv));
        }
        // reduce over the 16 candidate columns (lane bits 0-3)
#pragma unroll
        for (int off = 1; off < 16; off <<= 1) {
            vm0 = fminf(vm0, __shfl_xor(vm0, off, 64));
            vm1 = fminf(vm1, __shfl_xor(vm1, off, 64));
            vm2 = fminf(vm2, __shfl_xor(vm2, off, 64));
            vm3 = fminf(vm3, __shfl_xor(vm3, off, 64));
        }
        if (am == 0) {            // lanes 0,16,32,48 write rows aq*4+r
            pk[g][h * 4 + seg][aq * 4 + 0] = vm0;
            pk[g][h * 4 + seg][aq * 4 + 1] = vm1;
            pk[g][h * 4 + seg][aq * 4 + 2] = vm2;
            pk[g][h * 4 + seg][aq * 4 + 3] = vm3;
        }
    }
    __syncthreads();                          // barrier 1: pk + cnt visible

    // h==0 waves: 11th smallest of 16 segment minima -> tau (+MARGIN)
    if (h == 0) {
        float md[KNN + 1];
#pragma unroll
        for (int s = 0; s <= KNN; ++s) md[s] = F32_INF;
        const int qsel = lane & 15;
#pragma unroll
        for (int cc = 0; cc < 16; ++cc) {
            float d = pk[g][cc][qsel];
#pragma unroll
            for (int u = 0; u <= KNN; ++u) {
                const float lo = fminf(md[u], d);
                d = fmaxf(md[u], d);
                md[u] = lo;
            }
        }
        if (lane < 16) tau_s[lq_base + lane] = md[KNN] + MARGIN;
    }
    __syncthreads();                          // barrier 2: tau visible

    const float tq0 = tau_s[lq_base + aq * 4 + 0];
    const float tq1 = tau_s[lq_base + aq * 4 + 1];
    const float tq2 = tau_s[lq_base + aq * 4 + 2];
    const float tq3 = tau_s[lq_base + aq * 4 + 3];

    // ---------------- pass 2: filter via v~, exact keys on hit ----------------
    for (int ti = 0; ti < 128; ++ti) {
        const int c0 = cb0 + ti * 16;
        const uint4 brec = (aq < 2) ? bfp[(size_t)(c0 + am) * 2 + aq] : zrec;
        const bf16x8 bfrag = __builtin_bit_cast(bf16x8, brec);
        const float pwv = pwp[c0 + am];
        f32x4 acc = {0.f, 0.f, 0.f, 0.f};
        acc = __builtin_amdgcn_mfma_f32_16x16x32_bf16(afrag, bfrag, acc, 0, 0, 0);
        const int jc = c0 + am;
#pragma unroll
        for (int r = 0; r < 4; ++r) {
            const float v = fmaf(-2.0f, acc[r], pwv);
            const float tqr = (r == 0) ? tq0 : (r == 1) ? tq1 : (r == 2) ? tq2 : tq3;
            if (__builtin_expect(v <= tqr, 0)) {
                const float4 qfr = (r == 0) ? qf0 : (r == 1) ? qf1 : (r == 2) ? qf2 : qf3;
                const float4 p = pb[jc];
                // EXACT key: bitwise-identical to R1-R14's d2 expression
                const float dot = fmaf(p.z, qfr.z, fmaf(p.y, qfr.y, p.x * qfr.x));
                const float d2 = fmaf(-2.0f, dot, qfr.w + p.w);
                const unsigned int fb = __float_as_uint(d2);
                const unsigned int mo =
                    fb ^ ((unsigned int)((int)fb >> 31) | 0x80000000u);  // monotone
                const unsigned long long key =
                    ((unsigned long long)mo << 13) | (unsigned long long)(unsigned)jc;
                const int lq = lq_base + aq * 4 + r;
                const int slot = atomicAdd(&cnt[lq], 1);
                if (slot < CAP) coll[slot][lq] = key;
            }
        }
    }
    __syncthreads();

    // ---------------- phase 3: top-11 bubble, filter self by index ----------
    if (t < 32) {
        const int m = cnt[t];
        int mc = m;
#pragma unroll
        for (int off = 1; off < 32; off <<= 1)
            mc = max(mc, __shfl_xor(mc, off, 64));
        mc = __builtin_amdgcn_readfirstlane(mc);

        const int n = (bx & 255) * 32 + t;    // this lane's batch-local query

        unsigned long long md[KNN + 1];
#pragma unroll
        for (int s = 0; s <= KNN; ++s) md[s] = ~0ULL;

        if (mc <= CAP) {
            for (int cc = 0; cc < mc; ++cc) {
                unsigned long long key = (cc < m) ? coll[cc][t] : ~0ULL;
#pragma unroll
                for (int u = 0; u <= KNN; ++u) {
                    const bool lt = key < md[u];
                    const unsigned long long lo = lt ? key : md[u];
                    key = lt ? md[u] : key;
                    md[u] = lo;
                }
            }
        } else {
            // exact serial fallback (never expected): full rescan
            const float4 qv = pb[n];
            for (int j = 0; j < NPTS; ++j) {
                const float4 p = pb[j];
                const float dot = fmaf(p.z, qv.z, fmaf(p.y, qv.y, p.x * qv.x));
                const float d2 = fmaf(-2.0f, dot, qv.w + p.w);
                const unsigned int fb = __float_as_uint(d2);
                const unsigned int mm =
                    fb ^ ((unsigned int)((int)fb >> 31) | 0x80000000u);
                unsigned long long key =
                    ((unsigned long long)mm << 13) | (unsigned long long)j;
                key = (j == n) ? ~0ULL : key;
#pragma unroll
                for (int u = 0; u <= KNN; ++u) {
                    const bool lt = key < md[u];
                    const unsigned long long lo = lt ? key : md[u];
                    key = lt ? md[u] : key;
                    md[u] = lo;
                }
            }
        }

        unsigned short* outp = knn_idx + ((size_t)b * NPTS + n) * KNN;
        int outc = 0;
#pragma unroll
        for (int u = 0; u <= KNN; ++u) {
            const int idx = (int)(md[u] & 8191u);
            if (outc < KNN && idx != n) outp[outc++] = (unsigned short)idx;
        }
    }
}

// ---------------------------------------------------------------------------
// Features + MLP (unchanged from R14 / best measured config).
// ---------------------------------------------------------------------------
__global__ __launch_bounds__(256) void feat_mlp_kernel(const float4* __restrict__ pts4,
                                                       const float* __restrict__ W1,
                                                       const float* __restrict__ b1,
                                                       const float* __restrict__ W2,
                                                       const float* __restrict__ b2,
                                                       const unsigned short* __restrict__ knn_idx,
                                                       float* __restrict__ out) {
    __shared__ float w1s[NF * 68];            // padded stride
    __shared__ float b1s[HID];
    __shared__ float w2s[HID * 3];
    __shared__ float b2s[3];
    __shared__ float fs[64][NF + 1];          // stride 77

    const int t = threadIdx.x;
    for (int idx = t; idx < NF * HID; idx += 256)
        w1s[(idx >> 6) * 68 + (idx & 63)] = W1[idx];
    if (t < HID) b1s[t] = b1[t];
    if (t < HID * 3) w2s[t] = W2[t];
    if (t < 3) b2s[t] = b2[t];

    const int pl   = t >> 2;                  // point slot 0..63
    const int subh = t & 1;                   // hidden half
    const int subf = (t >> 1) & 1;            // feature half
    const int gid = blockIdx.x * 64 + pl;     // 0..32767
    const int b = gid >> 13;
    const int n = gid & (NPTS - 1);
    const float4* pb = pts4 + b * NPTS;

    if ((t & 3) == 0) {                       // one lane per quad builds
        const float4 cq = pb[n];
        const float cx = cq.x, cy = cq.y, cz = cq.z;

        float nx[KNN], ny[KNN], nz[KNN];
        const unsigned short* ki = knn_idx + (size_t)gid * KNN;
#pragma unroll
        for (int k = 0; k < KNN; ++k) {
            const int j = ki[k];
            const float4 p = pb[j];
            nx[k] = p.x; ny[k] = p.y; nz[k] = p.z;
        }

        float* fr = fs[pl];
        fr[0] = cx; fr[1] = cy; fr[2] = cz;
#pragma unroll
        for (int k = 0; k < KNN; ++k) {
            fr[3 + 3 * k + 0] = nx[k];
            fr[3 + 3 * k + 1] = ny[k];
            fr[3 + 3 * k + 2] = nz[k];
        }
#pragma unroll
        for (int k = 0; k < KNN; ++k) {
            fr[33 + 3 * k + 0] = nx[k] - cx;
            fr[33 + 3 * k + 1] = ny[k] - cy;
            fr[33 + 3 * k + 2] = nz[k] - cz;
        }
#pragma unroll
        for (int k = 0; k < KNN; ++k) {
            const float rx = nx[k] - cx, ry = ny[k] - cy, rz = nz[k] - cz;
            fr[63 + k] = sqrtf(fmaf(rz, rz, fmaf(ry, ry, rx * rx)));
        }

        float mx = 0.f, my = 0.f, mz = 0.f;
#pragma unroll
        for (int k = 0; k < KNN; ++k) { mx += nx[k]; my += ny[k]; mz += nz[k]; }
        mx *= (1.0f / KNN); my *= (1.0f / KNN); mz *= (1.0f / KNN);
        float c00 = 0.f, c01 = 0.f, c02 = 0.f, c11 = 0.f, c12 = 0.f, c22 = 0.f;
#pragma unroll
        for (int k = 0; k < KNN; ++k) {
            const float ex = nx[k] - mx, ey = ny[k] - my, ez = nz[k] - mz;
            c00 = fmaf(ex, ex, c00); c01 = fmaf(ex, ey, c01); c02 = fmaf(ex, ez, c02);
            c11 = fmaf(ey, ey, c11); c12 = fmaf(ey, ez, c12); c22 = fmaf(ez, ez, c22);
        }
        const float sc = 1.0f / (KNN - 1);
        c00 *= sc; c01 *= sc; c02 *= sc; c11 *= sc; c12 *= sc; c22 *= sc;

        // fp32 closed-form symmetric 3x3 eigenvalues
        const float qd = (c00 + c11 + c22) * (1.0f / 3.0f);
        const float pp1 = c01 * c01 + c02 * c02 + c12 * c12;
        const float d00 = c00 - qd, d11 = c11 - qd, d22 = c22 - qd;
        const float p2 = d00 * d00 + d11 * d11 + d22 * d22 + 2.0f * pp1;
        float l1, l2, l3;
        if (p2 < 1e-30f) {
            l1 = l2 = l3 = qd;
        } else {
            const float p = sqrtf(p2 * (1.0f / 6.0f));
            const float inv = 1.0f / p;
            const float e00 = d00 * inv, e11 = d11 * inv, e22 = d22 * inv;
            const float e01 = c01 * inv, e02 = c02 * inv, e12 = c12 * inv;
            float detB = e00 * (e11 * e22 - e12 * e12)
                       - e01 * (e01 * e22 - e12 * e02)
                       + e02 * (e01 * e12 - e11 * e02);
            float r = 0.5f * detB;
            r = fminf(1.0f, fmaxf(-1.0f, r));
            const float phi = acosf(r) * (1.0f / 3.0f);
            l1 = qd + 2.0f * p * __cosf(phi);                          // largest
            l3 = qd + 2.0f * p * __cosf(phi + 2.0943951023931953f);    // smallest
            l2 = 3.0f * qd - l1 - l3;
        }
        fr[73] = (l1 - l2) / l1;
        fr[74] = (l2 - l3) / l1;
        fr[75] = l3 / l1;
    }

    __syncthreads();   // weights + features visible

    const float* fr = fs[pl];
    const int f0 = subf * 38;

    float h[32];
#pragma unroll
    for (int j = 0; j < 32; ++j) h[j] = (subf == 0) ? b1s[subh * 32 + j] : 0.0f;

#pragma unroll 2
    for (int ff = 0; ff < 38; ++ff) {
        const int f = f0 + ff;
        const float v = fr[f];
        const float4* w4 = reinterpret_cast<const float4*>(w1s + f * 68 + subh * 32);
#pragma unroll
        for (int j4 = 0; j4 < 8; ++j4) {
            const float4 w = w4[j4];
            h[4 * j4 + 0] = fmaf(v, w.x, h[4 * j4 + 0]);
            h[4 * j4 + 1] = fmaf(v, w.y, h[4 * j4 + 1]);
            h[4 * j4 + 2] = fmaf(v, w.z, h[4 * j4 + 2]);
            h[4 * j4 + 3] = fmaf(v, w.w, h[4 * j4 + 3]);
        }
    }

    // combine feature halves (lanes differing in bit 1)
#pragma unroll
    for (int j = 0; j < 32; ++j) h[j] += __shfl_xor(h[j], 2, 64);

    float o0 = 0.f, o1 = 0.f, o2 = 0.f;
#pragma unroll
    for (int j = 0; j < 32; ++j) {
        const float r = fmaxf(h[j], 0.0f);
        const int jj = subh * 32 + j;
        o0 = fmaf(r, w2s[jj * 3 + 0], o0);
        o1 = fmaf(r, w2s[jj * 3 + 1], o1);
        o2 = fmaf(r, w2s[jj * 3 + 2], o2);
    }
    // combine hidden halves (lanes differing in bit 0)
    o0 += __shfl_xor(o0, 1, 64);
    o1 += __shfl_xor(o1, 1, 64);
    o2 += __shfl_xor(o2, 1, 64);

    if ((t & 3) == 0) {
        float* op = out + (size_t)gid * 3;
        op[0] = fmaxf(o0 + b2s[0], 0.0f);
        op[1] = fmaxf(o1 + b2s[1], 0.0f);
        op[2] = fmaxf(o2 + b2s[2], 0.0f);
    }
}

extern "C" void kernel_launch(void* const* d_in, const int* in_sizes, int n_in,
                              void* d_out, int out_size, void* d_ws, size_t ws_size,
                              hipStream_t stream) {
    const float* cloud = (const float*)d_in[0];   // [4,8192,3]
    const float* W1    = (const float*)d_in[1];   // [76,64]
    const float* b1    = (const float*)d_in[2];   // [64]
    const float* W2    = (const float*)d_in[3];   // [64,3]
    const float* b2    = (const float*)d_in[4];   // [3]
    float* out = (float*)d_out;                   // [4,8192,3]

    char* ws = (char*)d_ws;
    float4* pts4 = (float4*)ws;                                  // 512 KB @ 0
    unsigned short* knn = (unsigned short*)(ws + 512 * 1024);    // 640 KB
    uint4* bfrec = (uint4*)(ws + 1184 * 1024);                   // 1 MB (32B/pt)
    float* pwa = (float*)(ws + 2208 * 1024);                     // 128 KB

    prep_kernel<<<dim3(128), dim3(256), 0, stream>>>(cloud, pts4, bfrec, pwa);
    knn_kernel<<<dim3(1024), dim3(512), 0, stream>>>(pts4, bfrec, pwa, knn);
    feat_mlp_kernel<<<dim3(512), dim3(256), 0, stream>>>(pts4, W1, b1, W2, b2, knn, out);
}

// Round 16
// 181.452 us; speedup vs baseline: 2.0147x; 2.0147x over previous
//
#include <hip/hip_runtime.h>
#include <math.h>

#define KNN    10
#define NPTS   8192
#define HID    64
#define NF     76
#define Q      16                // queries per wave
#define CAP    64                // pass-2 collection capacity per query
#define F32_INF __uint_as_float(0x7F800000u)

__device__ __forceinline__ float rl(float v, int lane) {
    return __int_as_float(__builtin_amdgcn_readlane(__float_as_int(v), lane));
}

// ---------------------------------------------------------------------------
// Prep: pts4[i] = (x, y, z, x^2+y^2+z^2)  (w chain identical to all rounds).
// ---------------------------------------------------------------------------
__global__ __launch_bounds__(256) void prep_kernel(const float* __restrict__ cloud,
                                                   float4* __restrict__ pts4) {
    const int i = blockIdx.x * 256 + threadIdx.x;      // 0..32767
    const float x = cloud[i * 3 + 0];
    const float y = cloud[i * 3 + 1];
    const float z = cloud[i * 3 + 2];
    pts4[i] = make_float4(x, y, z, fmaf(z, z, fmaf(y, y, x * x)));
}

// ---------------------------------------------------------------------------
// KNN — exact R14 kernel (best measured: 113.6us, absmax 4.39e-3).
// R15's MFMA variant regressed 2.7x: d=3 => K=12 skinny tiles, 16 cands per
// MFMA, delivery overhead 25x the matrix math. VALU transposed scan wins.
// Block 512 thr = 8 waves = 2 query-groups x 4 candidate-quarters; grid 1024.
// ---------------------------------------------------------------------------
__global__ __launch_bounds__(512) void knn_kernel(const float4* __restrict__ pts4,
                                                  unsigned short* __restrict__ knn_idx) {
    __shared__ unsigned long long coll[CAP][33];   // [slot][block query+pad], 16.9 KB
    __shared__ float pk[8][Q][17];                 // chunk minima, 8.7 KB
    __shared__ float tau_s[32];
    __shared__ int   cnt[32];

    const int t    = threadIdx.x;
    const int w    = t >> 6;                  // wave 0..7
    const int lane = t & 63;
    const int g    = w >> 2;                  // query group 0..1
    const int h    = w & 3;                   // candidate quarter 0..3
    const int bx   = blockIdx.x;              // 0..1023
    const int b    = bx >> 8;                 // batch
    const int n_base = (bx & 255) * 32 + g * Q;   // batch-local first query of group
    const int lq_base = g * Q;                // block-local query base
    const int cb0 = h * (NPTS / 4);           // candidate base for this wave

    const float4* pb = pts4 + b * NPTS;

    if (t < 32) cnt[t] = 0;                   // visible after barrier 1

    float qxs[Q], qys[Q], qzs[Q], qss[Q];
#pragma unroll
    for (int qq = 0; qq < Q; ++qq) {
        const float4 qv = pb[n_base + qq];
        qxs[qq] = qv.x; qys[qq] = qv.y; qzs[qq] = qv.z; qss[qq] = qv.w;
    }

    // ---------------- pass 1: per-lane minima over this quarter ----------------
    float vmin[Q];
#pragma unroll
    for (int qq = 0; qq < Q; ++qq) vmin[qq] = F32_INF;

    float4 cp = pb[cb0 + lane];               // coalesced vector load
    for (int ti = 0; ti < NPTS / 4 / 64; ++ti) {  // 32 tiles
        const float4 np = (ti < NPTS / 4 / 64 - 1) ? pb[cb0 + (ti + 1) * 64 + lane] : cp;
        const float a2x = -2.0f * cp.x;       // once per tile, amortized /16
        const float a2y = -2.0f * cp.y;
        const float a2z = -2.0f * cp.z;
        const float aw  = cp.w;
#pragma unroll
        for (int qq = 0; qq < Q; ++qq) {
            const float v = fmaf(a2x, qxs[qq], fmaf(a2y, qys[qq], fmaf(a2z, qzs[qq], aw)));
            vmin[qq] = fminf(vmin[qq], v);    // self included (rank arg handles it)
        }
        cp = np;
    }

#pragma unroll
    for (int qq = 0; qq < Q; ++qq) {
        float v = vmin[qq];
        v = fminf(v, __shfl_xor(v, 32, 64));
        v = fminf(v, __shfl_xor(v, 16, 64));
        if (lane < 16) pk[w][qq][lane] = v;
    }
    __syncthreads();                          // barrier 1: pk + cnt visible

    // h==0 waves (w = g*4): 11th smallest of 64 chunk minima -> tau for group
    if (h == 0) {
        float md[KNN + 1];
#pragma unroll
        for (int s = 0; s <= KNN; ++s) md[s] = F32_INF;
        const int qsel = lane & 15;           // 4-way replicated
#pragma unroll
        for (int cc = 0; cc < 64; ++cc) {
            float d = pk[g * 4 + (cc >> 4)][qsel][cc & 15];
#pragma unroll
            for (int u = 0; u <= KNN; ++u) {
                const float lo = fminf(md[u], d);
                d = fmaxf(md[u], d);
                md[u] = lo;
            }
        }
        if (lane < 16) tau_s[lq_base + lane] = md[KNN] + 1e-3f;
    }
    __syncthreads();                          // barrier 2: tau visible

    float taum[Q];
    {
        const float tv = tau_s[lq_base + (lane & 15)];
#pragma unroll
        for (int qq = 0; qq < Q; ++qq) taum[qq] = rl(tv, qq);   // -> SGPRs
    }

    // ---------------- pass 2: collect hits incl. self (rare) ----------------
    float4 cp2 = pb[cb0 + lane];
    int jcur = cb0 + lane;
    for (int ti = 0; ti < NPTS / 4 / 64; ++ti) {
        const float4 np = (ti < NPTS / 4 / 64 - 1) ? pb[cb0 + (ti + 1) * 64 + lane] : cp2;
        const float a2x = -2.0f * cp2.x;
        const float a2y = -2.0f * cp2.y;
        const float a2z = -2.0f * cp2.z;
        const float aw  = cp2.w;
#pragma unroll
        for (int qq = 0; qq < Q; ++qq) {
            const float v = fmaf(a2x, qxs[qq], fmaf(a2y, qys[qq], fmaf(a2z, qzs[qq], aw)));
            if (__builtin_expect(v <= taum[qq], 0)) {
                const float px = -0.5f * a2x;
                const float py = -0.5f * a2y;
                const float pz = -0.5f * a2z;
                const float dot = fmaf(pz, qzs[qq], fmaf(py, qys[qq], px * qxs[qq]));
                const float d2 = fmaf(-2.0f, dot, qss[qq] + aw);
                const unsigned int fb = __float_as_uint(d2);
                const unsigned int m =
                    fb ^ ((unsigned int)((int)fb >> 31) | 0x80000000u);  // monotone
                const unsigned long long key =
                    ((unsigned long long)m << 13) | (unsigned long long)(unsigned)jcur;
                const int slot = atomicAdd(&cnt[lq_base + qq], 1);
                if (slot < CAP) coll[slot][lq_base + qq] = key;
            }
        }
        cp2 = np; jcur += 64;
    }
    __syncthreads();

    // ---------------- phase 3: top-11 bubble, filter self by index ----------
    if (t < 32) {
        const int m = cnt[t];
        int mc = m;
#pragma unroll
        for (int off = 1; off < 32; off <<= 1)        // 32 active lanes only
            mc = max(mc, __shfl_xor(mc, off, 64));
        mc = __builtin_amdgcn_readfirstlane(mc);

        const int n = (bx & 255) * 32 + t;    // this lane's batch-local query

        unsigned long long md[KNN + 1];
#pragma unroll
        for (int s = 0; s <= KNN; ++s) md[s] = ~0ULL;

        if (mc <= CAP) {
            for (int cc = 0; cc < mc; ++cc) {
                unsigned long long key = (cc < m) ? coll[cc][t] : ~0ULL;
#pragma unroll
                for (int u = 0; u <= KNN; ++u) {
                    const bool lt = key < md[u];
                    const unsigned long long lo = lt ? key : md[u];
                    key = lt ? md[u] : key;
                    md[u] = lo;
                }
            }
        } else {
            const float4 qv = pb[n];
            for (int j = 0; j < NPTS; ++j) {
                const float4 p = pb[j];
                const float dot = fmaf(p.z, qv.z, fmaf(p.y, qv.y, p.x * qv.x));
                const float d2 = fmaf(-2.0f, dot, qv.w + p.w);
                const unsigned int fb = __float_as_uint(d2);
                const unsigned int mm =
                    fb ^ ((unsigned int)((int)fb >> 31) | 0x80000000u);
                unsigned long long key =
                    ((unsigned long long)mm << 13) | (unsigned long long)j;
                key = (j == n) ? ~0ULL : key;
#pragma unroll
                for (int u = 0; u <= KNN; ++u) {
                    const bool lt = key < md[u];
                    const unsigned long long lo = lt ? key : md[u];
                    key = lt ? md[u] : key;
                    md[u] = lo;
                }
            }
        }

        unsigned short* outp = knn_idx + ((size_t)b * NPTS + n) * KNN;
        int outc = 0;
#pragma unroll
        for (int u = 0; u <= KNN; ++u) {
            const int idx = (int)(md[u] & 8191u);
            if (outc < KNN && idx != n) outp[outc++] = (unsigned short)idx;
        }
    }
}

// ---------------------------------------------------------------------------
// Features + MLP, 8 threads/point (R15 change): subh (2) x subf (4).
// Block 512 thr = 64 points, grid 512 -> 4096 waves = 4/SIMD (2x R14's
// latency-hiding). Total w1s ds_read_b128 work is layout-invariant; this
// adds only the h-combine shuffles (xor 2,4). Feature build stays serial
// on one lane per point (no butterfly cov — that's what sank R13).
// LDS ~41 KB -> 3 blocks/CU = 24 waves/CU.
// ---------------------------------------------------------------------------
__global__ __launch_bounds__(512) void feat_mlp_kernel(const float4* __restrict__ pts4,
                                                       const float* __restrict__ W1,
                                                       const float* __restrict__ b1,
                                                       const float* __restrict__ W2,
                                                       const float* __restrict__ b2,
                                                       const unsigned short* __restrict__ knn_idx,
                                                       float* __restrict__ out) {
    __shared__ float w1s[NF * 68];            // padded stride, 20.7 KB
    __shared__ float b1s[HID];
    __shared__ float w2s[HID * 3];
    __shared__ float b2s[3];
    __shared__ float fs[64][NF + 1];          // stride 77, 19.7 KB

    const int t = threadIdx.x;
    for (int idx = t; idx < NF * HID; idx += 512)
        w1s[(idx >> 6) * 68 + (idx & 63)] = W1[idx];
    if (t < HID) b1s[t] = b1[t];
    if (t < HID * 3) w2s[t] = W2[t];
    if (t < 3) b2s[t] = b2[t];

    const int pl   = t >> 3;                  // point slot 0..63
    const int s    = t & 7;                   // sub-lane within point group
    const int subh = s & 1;                   // hidden half (32 units)
    const int subf = s >> 1;                  // feature quarter (19 features)
    const int gid = blockIdx.x * 64 + pl;     // 0..32767
    const int b = gid >> 13;
    const int n = gid & (NPTS - 1);
    const float4* pb = pts4 + b * NPTS;

    if (s == 0) {                             // one lane per point builds
        const float4 cq = pb[n];
        const float cx = cq.x, cy = cq.y, cz = cq.z;

        float nx[KNN], ny[KNN], nz[KNN];
        const unsigned short* ki = knn_idx + (size_t)gid * KNN;
#pragma unroll
        for (int k = 0; k < KNN; ++k) {
            const int j = ki[k];
            const float4 p = pb[j];
            nx[k] = p.x; ny[k] = p.y; nz[k] = p.z;
        }

        float* fr = fs[pl];
        fr[0] = cx; fr[1] = cy; fr[2] = cz;
#pragma unroll
        for (int k = 0; k < KNN; ++k) {
            fr[3 + 3 * k + 0] = nx[k];
            fr[3 + 3 * k + 1] = ny[k];
            fr[3 + 3 * k + 2] = nz[k];
        }
#pragma unroll
        for (int k = 0; k < KNN; ++k) {
            fr[33 + 3 * k + 0] = nx[k] - cx;
            fr[33 + 3 * k + 1] = ny[k] - cy;
            fr[33 + 3 * k + 2] = nz[k] - cz;
        }
#pragma unroll
        for (int k = 0; k < KNN; ++k) {
            const float rx = nx[k] - cx, ry = ny[k] - cy, rz = nz[k] - cz;
            fr[63 + k] = sqrtf(fmaf(rz, rz, fmaf(ry, ry, rx * rx)));
        }

        float mx = 0.f, my = 0.f, mz = 0.f;
#pragma unroll
        for (int k = 0; k < KNN; ++k) { mx += nx[k]; my += ny[k]; mz += nz[k]; }
        mx *= (1.0f / KNN); my *= (1.0f / KNN); mz *= (1.0f / KNN);
        float c00 = 0.f, c01 = 0.f, c02 = 0.f, c11 = 0.f, c12 = 0.f, c22 = 0.f;
#pragma unroll
        for (int k = 0; k < KNN; ++k) {
            const float ex = nx[k] - mx, ey = ny[k] - my, ez = nz[k] - mz;
            c00 = fmaf(ex, ex, c00); c01 = fmaf(ex, ey, c01); c02 = fmaf(ex, ez, c02);
            c11 = fmaf(ey, ey, c11); c12 = fmaf(ey, ez, c12); c22 = fmaf(ez, ez, c22);
        }
        const float sc = 1.0f / (KNN - 1);
        c00 *= sc; c01 *= sc; c02 *= sc; c11 *= sc; c12 *= sc; c22 *= sc;

        // fp32 closed-form symmetric 3x3 eigenvalues
        const float qd = (c00 + c11 + c22) * (1.0f / 3.0f);
        const float pp1 = c01 * c01 + c02 * c02 + c12 * c12;
        const float d00 = c00 - qd, d11 = c11 - qd, d22 = c22 - qd;
        const float p2 = d00 * d00 + d11 * d11 + d22 * d22 + 2.0f * pp1;
        float l1, l2, l3;
        if (p2 < 1e-30f) {
            l1 = l2 = l3 = qd;
        } else {
            const float p = sqrtf(p2 * (1.0f / 6.0f));
            const float inv = 1.0f / p;
            const float e00 = d00 * inv, e11 = d11 * inv, e22 = d22 * inv;
            const float e01 = c01 * inv, e02 = c02 * inv, e12 = c12 * inv;
            float detB = e00 * (e11 * e22 - e12 * e12)
                       - e01 * (e01 * e22 - e12 * e02)
                       + e02 * (e01 * e12 - e11 * e02);
            float r = 0.5f * detB;
            r = fminf(1.0f, fmaxf(-1.0f, r));
            const float phi = acosf(r) * (1.0f / 3.0f);
            l1 = qd + 2.0f * p * __cosf(phi);                          // largest
            l3 = qd + 2.0f * p * __cosf(phi + 2.0943951023931953f);    // smallest
            l2 = 3.0f * qd - l1 - l3;
        }
        fr[73] = (l1 - l2) / l1;
        fr[74] = (l2 - l3) / l1;
        fr[75] = l3 / l1;
    }

    __syncthreads();   // weights + features visible

    const float* fr = fs[pl];
    const int f0 = subf * 19;

    float h[32];
#pragma unroll
    for (int j = 0; j < 32; ++j) h[j] = (subf == 0) ? b1s[subh * 32 + j] : 0.0f;

#pragma unroll
    for (int ff = 0; ff < 19; ++ff) {
        const float v = fr[f0 + ff];
        const float4* w4 = reinterpret_cast<const float4*>(w1s + (f0 + ff) * 68 + subh * 32);
#pragma unroll
        for (int j4 = 0; j4 < 8; ++j4) {
            const float4 w = w4[j4];
            h[4 * j4 + 0] = fmaf(v, w.x, h[4 * j4 + 0]);
            h[4 * j4 + 1] = fmaf(v, w.y, h[4 * j4 + 1]);
            h[4 * j4 + 2] = fmaf(v, w.z, h[4 * j4 + 2]);
            h[4 * j4 + 3] = fmaf(v, w.w, h[4 * j4 + 3]);
        }
    }

    // combine feature quarters (lane bits 1-2 = subf)
#pragma unroll
    for (int j = 0; j < 32; ++j) {
        h[j] += __shfl_xor(h[j], 2, 64);
        h[j] += __shfl_xor(h[j], 4, 64);
    }

    // layer 2: this thread handles j in [subf*8, subf*8+8) of its h[32]
    float o0 = 0.f, o1 = 0.f, o2 = 0.f;
#pragma unroll
    for (int jj = 0; jj < 8; ++jj) {
        const int j = subf * 8 + jj;
        const float r = fmaxf(h[j], 0.0f);
        const int hidx = subh * 32 + j;
        o0 = fmaf(r, w2s[hidx * 3 + 0], o0);
        o1 = fmaf(r, w2s[hidx * 3 + 1], o1);
        o2 = fmaf(r, w2s[hidx * 3 + 2], o2);
    }
    // combine subf (bits 1,2) then subh (bit 0)
#pragma unroll
    for (int off = 1; off < 8; off <<= 1) {
        o0 += __shfl_xor(o0, off, 64);
        o1 += __shfl_xor(o1, off, 64);
        o2 += __shfl_xor(o2, off, 64);
    }

    if (s == 0) {
        float* op = out + (size_t)gid * 3;
        op[0] = fmaxf(o0 + b2s[0], 0.0f);
        op[1] = fmaxf(o1 + b2s[1], 0.0f);
        op[2] = fmaxf(o2 + b2s[2], 0.0f);
    }
}

extern "C" void kernel_launch(void* const* d_in, const int* in_sizes, int n_in,
                              void* d_out, int out_size, void* d_ws, size_t ws_size,
                              hipStream_t stream) {
    const float* cloud = (const float*)d_in[0];   // [4,8192,3]
    const float* W1    = (const float*)d_in[1];   // [76,64]
    const float* b1    = (const float*)d_in[2];   // [64]
    const float* W2    = (const float*)d_in[3];   // [64,3]
    const float* b2    = (const float*)d_in[4];   // [3]
    float* out = (float*)d_out;                   // [4,8192,3]

    float4* pts4 = (float4*)d_ws;                                          // 512 KB
    unsigned short* knn = (unsigned short*)((char*)d_ws + 4 * NPTS * 16);  // 640 KB

    prep_kernel<<<dim3(128), dim3(256), 0, stream>>>(cloud, pts4);
    knn_kernel<<<dim3(1024), dim3(512), 0, stream>>>(pts4, knn);
    feat_mlp_kernel<<<dim3(512), dim3(512), 0, stream>>>(pts4, W1, b1, W2, b2, knn, out);
}